// Round 1
// baseline (460.754 us; speedup 1.0000x reference)
//
#include <hip/hip_runtime.h>
#include <hip/hip_bf16.h>

using s8v  = __attribute__((ext_vector_type(8))) short;
using f32x4 = __attribute__((ext_vector_type(4))) float;

#define N_TOT 100352      // 32*56*56
#define WT_ELEMS 589824   // 9*256*256
#define XT_ELEMS 27557888 // 32*58*58*256
#define WS_NEED  56295424 // 2*(WT_ELEMS+XT_ELEMS)

__device__ __forceinline__ unsigned short f2bf(float f) {
    unsigned int u = __float_as_uint(f);
    unsigned int r = (u + 0x7FFF + ((u >> 16) & 1)) >> 16;  // RNE
    return (unsigned short)r;
}

__device__ __forceinline__ void gl_lds16(const void* g, void* l) {
    __builtin_amdgcn_global_load_lds(
        (const __attribute__((address_space(1))) unsigned int*)g,
        (__attribute__((address_space(3))) unsigned int*)l, 16, 0, 0);
}

// weights [O=256][C=256][9] fp32 -> Wt [9][256][256] bf16 (tap-major, c contiguous)
__global__ void prep_w(const float* __restrict__ w, unsigned short* __restrict__ wt) {
    int idx = blockIdx.x * 256 + threadIdx.x;   // 0..589823
    int tap = idx >> 16;
    int rem = idx & 65535;
    int o = rem >> 8, c = rem & 255;
    wt[idx] = f2bf(w[(o * 256 + c) * 9 + tap]);
}

// x [32][256][56][56] fp32 -> Xt [32][58][58][256] bf16, zero-padded NHWC
__global__ void prep_x(const float* __restrict__ x, unsigned short* __restrict__ xt) {
    int b  = blockIdx.x / 58;
    int hp = blockIdx.x % 58;
    int tid = threadIdx.x;
    unsigned short* rowout = xt + (size_t)(b * 58 + hp) * 58 * 256;
    if (hp == 0 || hp == 57) {
        uint4 z = {0u, 0u, 0u, 0u};
        uint4* p = (uint4*)rowout;
        for (int i = tid; i < 1856; i += 256) p[i] = z;   // 58*512B
        return;
    }
    int h = hp - 1;
    __shared__ unsigned short lds[56 * 264];   // row stride 264 (pad) to break conflicts
    #pragma unroll
    for (int it = 0; it < 14; ++it) {
        int idx = it * 256 + tid;          // 0..3583 float4s
        int c  = idx / 14;
        int w4 = idx - c * 14;
        float4 v = *(const float4*)(x + (((size_t)(b * 256 + c) * 56 + h) * 56 + w4 * 4));
        int wb = w4 * 4;
        lds[(wb + 0) * 264 + c] = f2bf(v.x);
        lds[(wb + 1) * 264 + c] = f2bf(v.y);
        lds[(wb + 2) * 264 + c] = f2bf(v.z);
        lds[(wb + 3) * 264 + c] = f2bf(v.w);
    }
    __syncthreads();
    // zero edge pixels 0 and 57 (512B each)
    {
        unsigned int* z1 = (unsigned int*)rowout;            // pixel 0
        unsigned int* z2 = (unsigned int*)(rowout + 57 * 256);
        if (tid < 128) z1[tid] = 0u; else z2[tid - 128] = 0u;
    }
    // interior pixels 1..56: 2 pixels per iter, uint (2 c's) per lane
    int c2 = tid & 127;
    int ph = tid >> 7;
    for (int w = 0; w < 56; w += 2) {
        int pw = w + ph;
        unsigned int v = *(const unsigned int*)&lds[pw * 264 + c2 * 2];
        *(unsigned int*)(rowout + (pw + 1) * 256 + c2 * 2) = v;
    }
}

// Implicit GEMM: out[o][n] = sum_{tap,c} Wt[tap][o][c] * Xt[pix(n)+tap][c]
// 128x128 tile, BK=32 (one 16x16x32 MFMA K-chunk), 4 waves, 4x4 frags each.
__global__ __launch_bounds__(256) void gemm_conv(const unsigned short* __restrict__ wt,
                                                 const unsigned short* __restrict__ xt,
                                                 float* __restrict__ out) {
    __shared__ __align__(16) char smA[8192];  // [chunk 0..3][m 0..127][16B]
    __shared__ __align__(16) char smB[8192];  // [chunk 0..3][n 0..127][16B]
    int bx = blockIdx.x;
    int mt = bx & 1, nt = bx >> 1;
    int tid  = threadIdx.x;
    int wave = tid >> 6, lane = tid & 63;
    int quad = lane >> 4, l16 = lane & 15;
    int wm = wave >> 1, wn = wave & 1;

    // A staging: wave==chunk (c-offset wave*8), lane -> o = mt*128 + mhalf*64 + lane
    const unsigned short* pA0 = wt + ((mt * 128 + lane) << 8) + wave * 8;
    char* ldsA0 = smA + wave * 2048;

    // B staging: pixel bases for n1 = nt*128+lane (nhalf 0), n2 = n1+64 (nhalf 1)
    int n1 = nt * 128 + lane;
    int b1 = n1 / 3136; int r1 = n1 - b1 * 3136; int h1 = r1 / 56; int w1 = r1 - h1 * 56;
    int n2 = n1 + 64;
    int b2 = n2 / 3136; int r2 = n2 - b2 * 3136; int h2 = r2 / 56; int w2 = r2 - h2 * 56;
    const unsigned short* pB1 = xt + (((size_t)(b1 * 58 + h1) * 58 + w1) << 8) + wave * 8;
    const unsigned short* pB2 = xt + (((size_t)(b2 * 58 + h2) * 58 + w2) << 8) + wave * 8;
    char* ldsB0 = smB + wave * 2048;

    // LDS frag read bases (loop-invariant)
    const char* ra = smA + quad * 2048;
    const char* rb = smB + quad * 2048;

    f32x4 acc[4][4] = {};

    for (int tap = 0; tap < 9; ++tap) {
        int dh = tap / 3;
        int dw = tap - dh * 3;
        int tofsB = (dh * 58 + dw) << 8;          // element offset into Xt (pixel shift)
        const unsigned short* pa = pA0 + tap * 65536;
        for (int cb = 0; cb < 8; ++cb) {
            const unsigned short* sa  = pa + cb * 32;
            const unsigned short* sb1 = pB1 + tofsB + cb * 32;
            const unsigned short* sb2 = pB2 + tofsB + cb * 32;
            gl_lds16(sa,          ldsA0);
            gl_lds16(sa + 16384,  ldsA0 + 1024);   // +64 o's
            gl_lds16(sb1,         ldsB0);
            gl_lds16(sb2,         ldsB0 + 1024);
            __syncthreads();
            s8v af[4], bf[4];
            #pragma unroll
            for (int i = 0; i < 4; ++i)
                af[i] = *(const s8v*)(ra + ((wm * 64 + i * 16 + l16) << 4));
            #pragma unroll
            for (int j = 0; j < 4; ++j)
                bf[j] = *(const s8v*)(rb + ((wn * 64 + j * 16 + l16) << 4));
            #pragma unroll
            for (int i = 0; i < 4; ++i)
                #pragma unroll
                for (int j = 0; j < 4; ++j)
                    acc[i][j] = __builtin_amdgcn_mfma_f32_16x16x32_bf16(af[i], bf[j], acc[i][j], 0, 0, 0);
            __syncthreads();
        }
    }

    // Epilogue: C/D layout col=lane&15 (n), row=quad*4+reg (m=o)
    float* op = out + (size_t)(mt * 128 + wm * 64 + quad * 4) * N_TOT + nt * 128 + wn * 64 + l16;
    #pragma unroll
    for (int i = 0; i < 4; ++i)
        #pragma unroll
        for (int r = 0; r < 4; ++r) {
            float* orow = op + (size_t)(i * 16 + r) * N_TOT;
            #pragma unroll
            for (int j = 0; j < 4; ++j)
                orow[j * 16] = acc[i][j][r];
        }
}

// Fallback if workspace too small: direct conv, one thread per output.
__global__ void conv_naive(const float* __restrict__ x, const float* __restrict__ wq,
                           float* __restrict__ out) {
    int f = blockIdx.x * 256 + threadIdx.x;
    int o = f / N_TOT;
    int n = f - o * N_TOT;
    int b = n / 3136; int r = n - b * 3136; int h = r / 56; int w = r - h * 56;
    const float* xb = x + (size_t)b * 256 * 3136;
    const float* wo = wq + o * 2304;
    float acc = 0.f;
    for (int c = 0; c < 256; ++c) {
        const float* xc = xb + c * 3136;
        const float* wc = wo + c * 9;
        #pragma unroll
        for (int dh = 0; dh < 3; ++dh) {
            int ih = h + dh - 1;
            if (ih < 0 || ih >= 56) continue;
            const float* xr = xc + ih * 56;
            #pragma unroll
            for (int dw = 0; dw < 3; ++dw) {
                int iw = w + dw - 1;
                if (iw >= 0 && iw < 56) acc += xr[iw] * wc[dh * 3 + dw];
            }
        }
    }
    out[f] = acc;
}

extern "C" void kernel_launch(void* const* d_in, const int* in_sizes, int n_in,
                              void* d_out, int out_size, void* d_ws, size_t ws_size,
                              hipStream_t stream) {
    const float* x = (const float*)d_in[0];
    const float* w = (const float*)d_in[1];
    float* out = (float*)d_out;
    if (ws_size >= (size_t)WS_NEED) {
        unsigned short* wt = (unsigned short*)d_ws;
        unsigned short* xt = wt + WT_ELEMS;
        prep_w<<<2304, 256, 0, stream>>>(w, wt);
        prep_x<<<32 * 58, 256, 0, stream>>>(x, xt);
        gemm_conv<<<1568, 256, 0, stream>>>(wt, xt, out);
    } else {
        conv_naive<<<N_TOT, 256, 0, stream>>>(x, w, out);
    }
}